// Round 1
// baseline (865.826 us; speedup 1.0000x reference)
//
#include <hip/hip_runtime.h>
#include <stdint.h>

// Fully-fused MLP: 1048576 x (64 -> 128 -> 128 -> 128 -> 128 -> 64)
// ReLU after all but last layer. fp32 in/out, bf16 MFMA compute (fp32 accum).
//
// Key idea of this version: ZERO LDS. The MFMA D-layout (lane q holds
// features mt*16+q*4+r) vs B-layout (lane q needs features s*32+q*8+j)
// mismatch is just a fixed permutation of the contraction index, so we
// absorb it into the stored weight matrices at convert time:
//   Wp[m][kp] = W[m][sigma(kp)],  sigma(kp)=32*(kp>>5)+16*((kp>>2)&1)
//                                          +4*((kp>>3)&3)+(kp&3)
// Then next-layer B-frag[s] = { pack(relu(acc[2s])), pack(relu(acc[2s+1])) }
// entirely in-lane: 4 v_max + 2 v_cvt_pk_bf16_f32 per 16x16 tile.
// No LDS round-trip, no cross-lane ops, no barriers, full-rate 16x16x32 MFMA.

#define D_IN   64
#define D_HID  128
#define D_OUT  64
#define N_HID  3                    // hidden layers (DEPTH-1)
#define NT     2                    // 16-row batch tiles per wave
#define WAVES  4                    // waves per block
#define ROWS_PER_WAVE  (NT * 16)    // 32
#define ROWS_PER_BLOCK (WAVES * ROWS_PER_WAVE)  // 128

typedef __attribute__((ext_vector_type(8))) short  short8;   // 8 x bf16 (4 VGPRs)
typedef __attribute__((ext_vector_type(4))) float  floatx4;  // MFMA C/D

union U4 { short8 s8; unsigned int u[4]; };

__device__ __forceinline__ unsigned int bfround(unsigned int u) {
  // round-to-nearest-even fp32 -> bf16 (top 16 bits)
  return u + 0x7fffu + ((u >> 16) & 1u);
}

// packed fp32x2 -> bf16x2 (RNE), 1 VALU op
__device__ __forceinline__ unsigned int cvt_pk_bf16(float lo, float hi) {
  unsigned int r;
  asm("v_cvt_pk_bf16_f32 %0, %1, %2" : "=v"(r) : "v"(lo), "v"(hi));
  return r;
}

__device__ __forceinline__ floatx4 mfma16(short8 a, short8 b, floatx4 c) {
  return __builtin_amdgcn_mfma_f32_16x16x32_bf16(a, b, c, 0, 0, 0);
}

// ---- tiny pre-pass: fp32 weights -> bf16 (k-permuted) in workspace -------
#define W_IN_ELEMS  (D_HID * D_IN)                   // 8192
#define W_HID_ELEMS (N_HID * D_HID * D_HID)          // 49152
#define W_OUT_ELEMS (D_OUT * D_HID)                  // 8192
#define W_TOTAL     (W_IN_ELEMS + W_HID_ELEMS + W_OUT_ELEMS)  // 65536

// stored contraction position kp -> source input-feature index
__device__ __forceinline__ int kperm(int kp) {
  return 32 * (kp >> 5) + 16 * ((kp >> 2) & 1) + 4 * ((kp >> 3) & 3) + (kp & 3);
}

__global__ void wconvert_kernel(const float* __restrict__ w_in,
                                const float* __restrict__ w_hid,
                                const float* __restrict__ w_out,
                                unsigned short* __restrict__ wbf) {
  const int i = blockIdx.x * 256 + threadIdx.x;
  float v;
  if (i < W_IN_ELEMS) {
    v = w_in[i];                                   // layer-0 input is x: natural order
  } else if (i < W_IN_ELEMS + W_HID_ELEMS) {
    const int j = i - W_IN_ELEMS;
    v = w_hid[(j & ~127) + kperm(j & 127)];        // permute columns (k order)
  } else {
    const int j = i - W_IN_ELEMS - W_HID_ELEMS;
    v = w_out[(j & ~127) + kperm(j & 127)];        // permute columns (k order)
  }
  wbf[i] = (unsigned short)(bfround(__float_as_uint(v)) >> 16);
}

// ---- hidden layer: K=128 (4 ksteps), M=128 (8 mtiles), ReLU, in-lane D->B ----
__device__ __forceinline__ void hidden_layer(const U4 (&bin)[NT][4], U4 (&bout)[NT][4],
                                             const unsigned short* __restrict__ wl,
                                             const float* __restrict__ bl,
                                             int q, int c) {
#pragma unroll
  for (int mt = 0; mt < 8; ++mt) {
    const unsigned short* wr = wl + (mt * 16 + c) * D_HID + q * 8;
    short8 a0 = *(const short8*)(wr);
    short8 a1 = *(const short8*)(wr + 32);
    short8 a2 = *(const short8*)(wr + 64);
    short8 a3 = *(const short8*)(wr + 96);
    floatx4 bias = *(const floatx4*)(bl + mt * 16 + q * 4);
#pragma unroll
    for (int nt = 0; nt < NT; ++nt) {
      floatx4 acc = bias;
      acc = mfma16(a0, bin[nt][0].s8, acc);
      acc = mfma16(a1, bin[nt][1].s8, acc);
      acc = mfma16(a2, bin[nt][2].s8, acc);
      acc = mfma16(a3, bin[nt][3].s8, acc);
      // D lane holds features mt*16+q*4+{0..3}; with permuted next-layer
      // weights this is exactly B-frag[mt>>1], u32 slots 2*(mt&1)+{0,1}.
      bout[nt][mt >> 1].u[2 * (mt & 1) + 0] =
          cvt_pk_bf16(fmaxf(acc[0], 0.f), fmaxf(acc[1], 0.f));
      bout[nt][mt >> 1].u[2 * (mt & 1) + 1] =
          cvt_pk_bf16(fmaxf(acc[2], 0.f), fmaxf(acc[3], 0.f));
    }
  }
}

// ---- main fused kernel ---------------------------------------------------
__global__ __launch_bounds__(WAVES * 64, 4) void mlp_kernel(
    const float* __restrict__ x,
    const unsigned short* __restrict__ wbf,
    const float* __restrict__ b_in,
    const float* __restrict__ b_hid,
    const float* __restrict__ b_out,
    float* __restrict__ out) {
  const int wv   = threadIdx.x >> 6;
  const int lane = threadIdx.x & 63;
  const int q    = lane >> 4;    // quad 0..3
  const int c    = lane & 15;    // batch col / A-operand row

  const int rowbase = (blockIdx.x * WAVES + wv) * ROWS_PER_WAVE;

  const unsigned short* w0 = wbf;                        // [128][64]  natural k
  const unsigned short* wh = wbf + W_IN_ELEMS;           // [3][128][128] permuted k
  const unsigned short* wo = wbf + W_IN_ELEMS + W_HID_ELEMS;  // [64][128] permuted k

  U4 ba[NT][4], bb[NT][4];

  // ---- layer 0 B-frags straight from x (natural k order, K=64) ----
#pragma unroll
  for (int nt = 0; nt < NT; ++nt) {
    const float* xr = x + (rowbase + nt * 16 + c) * D_IN + q * 8;
#pragma unroll
    for (int s = 0; s < 2; ++s) {
      floatx4 f0 = *(const floatx4*)(xr + s * 32);
      floatx4 f1 = *(const floatx4*)(xr + s * 32 + 4);
      ba[nt][s].u[0] = cvt_pk_bf16(f0[0], f0[1]);
      ba[nt][s].u[1] = cvt_pk_bf16(f0[2], f0[3]);
      ba[nt][s].u[2] = cvt_pk_bf16(f1[0], f1[1]);
      ba[nt][s].u[3] = cvt_pk_bf16(f1[2], f1[3]);
    }
  }

  // ---- layer 0 compute: M=128, K=64, ReLU -> bb (in-lane B-frags) ----
#pragma unroll
  for (int mt = 0; mt < 8; ++mt) {
    const unsigned short* wr = w0 + (mt * 16 + c) * D_IN + q * 8;
    short8 a0 = *(const short8*)(wr);
    short8 a1 = *(const short8*)(wr + 32);
    floatx4 bias = *(const floatx4*)(b_in + mt * 16 + q * 4);
#pragma unroll
    for (int nt = 0; nt < NT; ++nt) {
      floatx4 acc = bias;
      acc = mfma16(a0, ba[nt][0].s8, acc);
      acc = mfma16(a1, ba[nt][1].s8, acc);
      bb[nt][mt >> 1].u[2 * (mt & 1) + 0] =
          cvt_pk_bf16(fmaxf(acc[0], 0.f), fmaxf(acc[1], 0.f));
      bb[nt][mt >> 1].u[2 * (mt & 1) + 1] =
          cvt_pk_bf16(fmaxf(acc[2], 0.f), fmaxf(acc[3], 0.f));
    }
  }

  // ---- hidden layers: ping-pong bb -> ba -> bb -> ba ----
  hidden_layer(bb, ba, wh + 0 * (D_HID * D_HID), b_hid + 0 * D_HID, q, c);
  hidden_layer(ba, bb, wh + 1 * (D_HID * D_HID), b_hid + 1 * D_HID, q, c);
  hidden_layer(bb, ba, wh + 2 * (D_HID * D_HID), b_hid + 2 * D_HID, q, c);

  // ---- output layer: M=64 (4 mtiles), K=128, no activation ----
#pragma unroll
  for (int mt = 0; mt < 4; ++mt) {
    const unsigned short* wr = wo + (mt * 16 + c) * D_HID + q * 8;
    short8 a0 = *(const short8*)(wr);
    short8 a1 = *(const short8*)(wr + 32);
    short8 a2 = *(const short8*)(wr + 64);
    short8 a3 = *(const short8*)(wr + 96);
    floatx4 bias = *(const floatx4*)(b_out + mt * 16 + q * 4);
#pragma unroll
    for (int nt = 0; nt < NT; ++nt) {
      floatx4 acc = bias;
      acc = mfma16(a0, ba[nt][0].s8, acc);
      acc = mfma16(a1, ba[nt][1].s8, acc);
      acc = mfma16(a2, ba[nt][2].s8, acc);
      acc = mfma16(a3, ba[nt][3].s8, acc);
      // lane holds out[row = rowbase+nt*16+c][feat = mt*16 + q*4 + reg]
      *(floatx4*)(out + (rowbase + nt * 16 + c) * D_OUT + mt * 16 + q * 4) = acc;
    }
  }
}

extern "C" void kernel_launch(void* const* d_in, const int* in_sizes, int n_in,
                              void* d_out, int out_size, void* d_ws, size_t ws_size,
                              hipStream_t stream) {
  const float* x     = (const float*)d_in[0];
  const float* w_in  = (const float*)d_in[1];
  const float* b_in  = (const float*)d_in[2];
  const float* w_hid = (const float*)d_in[3];
  const float* b_hid = (const float*)d_in[4];
  const float* w_out = (const float*)d_in[5];
  const float* b_out = (const float*)d_in[6];
  float* out = (float*)d_out;
  unsigned short* wbf = (unsigned short*)d_ws;  // 131072 bytes used

  // weights fp32 -> bf16 with k-permutation (re-done every launch; ws re-poisoned)
  wconvert_kernel<<<W_TOTAL / 256, 256, 0, stream>>>(w_in, w_hid, w_out, wbf);

  const int N = in_sizes[0] / D_IN;            // 1048576
  const int blocks = N / ROWS_PER_BLOCK;       // 8192
  mlp_kernel<<<blocks, WAVES * 64, 0, stream>>>(x, wbf, b_in, b_hid, b_out, out);
}

// Round 2
// 481.218 us; speedup vs baseline: 1.7992x; 1.7992x over previous
//
#include <hip/hip_runtime.h>
#include <stdint.h>

// Fully-fused MLP: 1048576 x (64 -> 128 -> 128 -> 128 -> 128 -> 64)
// ReLU after all but last layer. fp32 in/out, bf16 MFMA compute (fp32 accum).
//
// This version: PERSISTENT blocks + ALL WEIGHTS IN LDS.
//  - wconvert pre-arranges all 5 layers' weights (with the verified in-lane
//    D->B k-permutation sigma for hidden/out layers) into per-fragment,
//    lane-linear order: frag(slot)[lane][8 elems]. One ds_read_b128 per
//    A-fragment, addr = base + lane*16 -> conflict-free, ~120cy latency.
//  - grid = 256 blocks of 512 threads (8 waves); each block stages 128KB of
//    weights + biases into LDS once, one __syncthreads, then loops over 8
//    row-chunks with ZERO barriers and ZERO global weight traffic.
//  - activations stay in registers (in-lane D->B via sigma), NT=4 rows*16
//    per wave per chunk.
//  - x for chunk it+1 prefetched into registers during chunk it's out-layer.

#define D_IN   64
#define D_HID  128
#define D_OUT  64
#define N_HID  3
#define NT     4                     // 16-row tiles per wave per chunk
#define WAVES  8
#define BLOCK  (WAVES * 64)          // 512
#define GRID   256
#define ITERS  8                     // 256 blocks * 512 rows * 8 = 1048576
#define ROWS_PER_WAVE (NT * 16)      // 64
#define ROWS_PER_BLOCK (WAVES * ROWS_PER_WAVE)  // 512

// ---- LDS layout (ushort element offsets) ----
// L0:  16 slots (mt*2+s),  [0, 8192)
// H l: 32 slots (mt*4+s),  [8192 + l*16384, ...)   l = 0..2
// OUT: 16 slots (mt*4+s),  [57344, 65536)
// biases (f32) after weights: 128 + 384 + 64 = 576 floats
#define L0_OFF   0
#define H_OFF    8192
#define H_STRIDE 16384
#define OUT_OFF  57344
#define W_ELEMS  65536
#define LDS_BYTES (W_ELEMS * 2 + 576 * 4)   // 133376

typedef __attribute__((ext_vector_type(8))) short  short8;   // 8 x bf16
typedef __attribute__((ext_vector_type(4))) float  floatx4;

union U4 { short8 s8; unsigned int u[4]; };

__device__ __forceinline__ unsigned int bfround(unsigned int u) {
  return u + 0x7fffu + ((u >> 16) & 1u);
}
__device__ __forceinline__ unsigned int cvt_pk_bf16(float lo, float hi) {
  unsigned int r;
  asm("v_cvt_pk_bf16_f32 %0, %1, %2" : "=v"(r) : "v"(lo), "v"(hi));
  return r;
}
__device__ __forceinline__ floatx4 mfma16(short8 a, short8 b, floatx4 c) {
  return __builtin_amdgcn_mfma_f32_16x16x32_bf16(a, b, c, 0, 0, 0);
}
__device__ __forceinline__ short8 ldsfrag(const unsigned short* p) {
  short8 v;
  __builtin_memcpy(&v, __builtin_assume_aligned(p, 16), 16);
  return v;
}
__device__ __forceinline__ floatx4 ldsbias(const float* p) {
  floatx4 v;
  __builtin_memcpy(&v, __builtin_assume_aligned(p, 16), 16);
  return v;
}

// ---- weight pre-arrangement -------------------------------------------------
#define W_IN_ELEMS  (D_HID * D_IN)
#define W_HID_ELEMS (N_HID * D_HID * D_HID)
#define W_OUT_ELEMS (D_OUT * D_HID)

// stored contraction position kp -> source input-feature index (verified r1)
__device__ __forceinline__ int kperm(int kp) {
  return 32 * (kp >> 5) + 16 * ((kp >> 2) & 1) + 4 * ((kp >> 3) & 3) + (kp & 3);
}

// output element i (0..65535) of the arranged bf16 weight image:
//   region slot layout: elem = region_off + slot*512 + lane*8 + j
//   lane fields: c = lane&15 (A row within mtile), q = lane>>4 (k chunk)
__global__ void wconvert_kernel(const float* __restrict__ w_in,
                                const float* __restrict__ w_hid,
                                const float* __restrict__ w_out,
                                unsigned short* __restrict__ wbf) {
  const int i = blockIdx.x * 256 + threadIdx.x;
  float v;
  if (i < H_OFF) {
    // layer 0: natural k (B comes from x). slot = mt*2+s
    const int mt = i >> 10;            // 1024 elems per mtile (2 slots)
    const int r  = i & 1023;
    const int s  = r >> 9;
    const int l  = (r >> 3) & 63;
    const int j  = r & 7;
    const int c = l & 15, q = l >> 4;
    v = w_in[(mt * 16 + c) * D_IN + s * 32 + q * 8 + j];
  } else if (i < OUT_OFF) {
    // hidden layer lh: permuted k. slot = mt*4+s
    const int ii = i - H_OFF;
    const int lh = ii >> 14;           // 16384 elems per layer
    const int r0 = ii & 16383;
    const int mt = r0 >> 11;           // 2048 elems per mtile (4 slots)
    const int r  = r0 & 2047;
    const int s  = r >> 9;
    const int l  = (r >> 3) & 63;
    const int j  = r & 7;
    const int c = l & 15, q = l >> 4;
    v = w_hid[lh * (D_HID * D_HID) + (mt * 16 + c) * D_HID + kperm(s * 32 + q * 8 + j)];
  } else {
    // out layer: permuted k. slot = mt*4+s
    const int ii = i - OUT_OFF;
    const int mt = ii >> 11;
    const int r  = ii & 2047;
    const int s  = r >> 9;
    const int l  = (r >> 3) & 63;
    const int j  = r & 7;
    const int c = l & 15, q = l >> 4;
    v = w_out[(mt * 16 + c) * D_HID + kperm(s * 32 + q * 8 + j)];
  }
  wbf[i] = (unsigned short)(bfround(__float_as_uint(v)) >> 16);
}

// ---- hidden layer: K=128 (4 ksteps), M=128 (8 mtiles), ReLU, in-lane D->B --
__device__ __forceinline__ void hidden_layer(const U4 (&bin)[NT][4], U4 (&bout)[NT][4],
                                             const unsigned short* __restrict__ fb,
                                             const float* __restrict__ blds,
                                             int lh, int q) {
  const unsigned short* wl = fb + H_OFF + lh * H_STRIDE;
  const float* bl = blds + 128 + lh * 128;
#pragma unroll
  for (int mt = 0; mt < 8; ++mt) {
    short8 a0 = ldsfrag(wl + (mt * 4 + 0) * 512);
    short8 a1 = ldsfrag(wl + (mt * 4 + 1) * 512);
    short8 a2 = ldsfrag(wl + (mt * 4 + 2) * 512);
    short8 a3 = ldsfrag(wl + (mt * 4 + 3) * 512);
    floatx4 bias = ldsbias(bl + mt * 16 + q * 4);
#pragma unroll
    for (int nt = 0; nt < NT; ++nt) {
      floatx4 acc = bias;
      acc = mfma16(a0, bin[nt][0].s8, acc);
      acc = mfma16(a1, bin[nt][1].s8, acc);
      acc = mfma16(a2, bin[nt][2].s8, acc);
      acc = mfma16(a3, bin[nt][3].s8, acc);
      bout[nt][mt >> 1].u[2 * (mt & 1) + 0] =
          cvt_pk_bf16(fmaxf(acc[0], 0.f), fmaxf(acc[1], 0.f));
      bout[nt][mt >> 1].u[2 * (mt & 1) + 1] =
          cvt_pk_bf16(fmaxf(acc[2], 0.f), fmaxf(acc[3], 0.f));
    }
  }
}

// ---- main fused kernel ------------------------------------------------------
__global__ __launch_bounds__(BLOCK, 2) void mlp_kernel(
    const float* __restrict__ x,
    const unsigned short* __restrict__ wbf,
    const float* __restrict__ b_in,
    const float* __restrict__ b_hid,
    const float* __restrict__ b_out,
    float* __restrict__ out) {
  extern __shared__ unsigned short wlds[];
  const int tid  = threadIdx.x;
  const int wv   = tid >> 6;
  const int lane = tid & 63;
  const int q    = lane >> 4;
  const int c    = lane & 15;

  // ---- one-time stage: 128KB weights + 2.25KB biases into LDS ----
  {
    uint4* dst = (uint4*)wlds;
    const uint4* src = (const uint4*)wbf;
#pragma unroll
    for (int i = 0; i < 16; ++i) dst[tid + i * BLOCK] = src[tid + i * BLOCK];
    float* bl = (float*)(wlds + W_ELEMS);
    if (tid < 128) bl[tid] = b_in[tid];
    if (tid < 384) bl[128 + tid] = b_hid[tid];
    if (tid < 64)  bl[512 + tid] = b_out[tid];
  }
  __syncthreads();
  // weights read-only from here on: NO further barriers, waves drift freely.

  const unsigned short* fb = wlds + lane * 8;   // lane-linear frag base
  const float* blds = (const float*)(wlds + W_ELEMS);

  U4 ba[NT][4], bb[NT][4];
  floatx4 px[16];   // x prefetch: NT rows x 4 float4 (64B/lane)

  // prologue: issue x loads for chunk 0
  {
    const int rb = blockIdx.x * ROWS_PER_BLOCK + wv * ROWS_PER_WAVE;
#pragma unroll
    for (int nt = 0; nt < NT; ++nt) {
      const float* xr = x + (rb + nt * 16 + c) * D_IN + q * 8;
      px[nt * 4 + 0] = *(const floatx4*)(xr);
      px[nt * 4 + 1] = *(const floatx4*)(xr + 4);
      px[nt * 4 + 2] = *(const floatx4*)(xr + 32);
      px[nt * 4 + 3] = *(const floatx4*)(xr + 36);
    }
  }

  for (int it = 0; it < ITERS; ++it) {
    const int rb = (it * GRID + blockIdx.x) * ROWS_PER_BLOCK + wv * ROWS_PER_WAVE;

    // ---- layer 0: nt-outer (JIT convert px -> 2 frags), M=128, K=64 ----
#pragma unroll
    for (int nt = 0; nt < NT; ++nt) {
      U4 b0, b1;
      b0.u[0] = cvt_pk_bf16(px[nt * 4 + 0][0], px[nt * 4 + 0][1]);
      b0.u[1] = cvt_pk_bf16(px[nt * 4 + 0][2], px[nt * 4 + 0][3]);
      b0.u[2] = cvt_pk_bf16(px[nt * 4 + 1][0], px[nt * 4 + 1][1]);
      b0.u[3] = cvt_pk_bf16(px[nt * 4 + 1][2], px[nt * 4 + 1][3]);
      b1.u[0] = cvt_pk_bf16(px[nt * 4 + 2][0], px[nt * 4 + 2][1]);
      b1.u[1] = cvt_pk_bf16(px[nt * 4 + 2][2], px[nt * 4 + 2][3]);
      b1.u[2] = cvt_pk_bf16(px[nt * 4 + 3][0], px[nt * 4 + 3][1]);
      b1.u[3] = cvt_pk_bf16(px[nt * 4 + 3][2], px[nt * 4 + 3][3]);
#pragma unroll
      for (int mt = 0; mt < 8; ++mt) {
        short8 a0 = ldsfrag(fb + L0_OFF + (mt * 2 + 0) * 512);
        short8 a1 = ldsfrag(fb + L0_OFF + (mt * 2 + 1) * 512);
        floatx4 acc = ldsbias(blds + mt * 16 + q * 4);
        acc = mfma16(a0, b0.s8, acc);
        acc = mfma16(a1, b1.s8, acc);
        bb[nt][mt >> 1].u[2 * (mt & 1) + 0] =
            cvt_pk_bf16(fmaxf(acc[0], 0.f), fmaxf(acc[1], 0.f));
        bb[nt][mt >> 1].u[2 * (mt & 1) + 1] =
            cvt_pk_bf16(fmaxf(acc[2], 0.f), fmaxf(acc[3], 0.f));
      }
    }

    // ---- hidden layers: ping-pong bb -> ba -> bb -> ba ----
    hidden_layer(bb, ba, fb, blds, 0, q);
    hidden_layer(ba, bb, fb, blds, 1, q);
    hidden_layer(bb, ba, fb, blds, 2, q);

    // ---- prefetch next chunk's x (covered by out-layer compute) ----
    if (it + 1 < ITERS) {
      const int nrb = ((it + 1) * GRID + blockIdx.x) * ROWS_PER_BLOCK + wv * ROWS_PER_WAVE;
#pragma unroll
      for (int nt = 0; nt < NT; ++nt) {
        const float* xr = x + (nrb + nt * 16 + c) * D_IN + q * 8;
        px[nt * 4 + 0] = *(const floatx4*)(xr);
        px[nt * 4 + 1] = *(const floatx4*)(xr + 4);
        px[nt * 4 + 2] = *(const floatx4*)(xr + 32);
        px[nt * 4 + 3] = *(const floatx4*)(xr + 36);
      }
    }

    // ---- output layer: M=64 (4 mtiles), K=128, no activation ----
#pragma unroll
    for (int mt = 0; mt < 4; ++mt) {
      short8 a0 = ldsfrag(fb + OUT_OFF + (mt * 4 + 0) * 512);
      short8 a1 = ldsfrag(fb + OUT_OFF + (mt * 4 + 1) * 512);
      short8 a2 = ldsfrag(fb + OUT_OFF + (mt * 4 + 2) * 512);
      short8 a3 = ldsfrag(fb + OUT_OFF + (mt * 4 + 3) * 512);
      floatx4 bias = ldsbias(blds + 512 + mt * 16 + q * 4);
#pragma unroll
      for (int nt = 0; nt < NT; ++nt) {
        floatx4 acc = bias;
        acc = mfma16(a0, ba[nt][0].s8, acc);
        acc = mfma16(a1, ba[nt][1].s8, acc);
        acc = mfma16(a2, ba[nt][2].s8, acc);
        acc = mfma16(a3, ba[nt][3].s8, acc);
        *(floatx4*)(out + (rb + nt * 16 + c) * D_OUT + mt * 16 + q * 4) = acc;
      }
    }
  }
}

extern "C" void kernel_launch(void* const* d_in, const int* in_sizes, int n_in,
                              void* d_out, int out_size, void* d_ws, size_t ws_size,
                              hipStream_t stream) {
  const float* x     = (const float*)d_in[0];
  const float* w_in  = (const float*)d_in[1];
  const float* b_in  = (const float*)d_in[2];
  const float* w_hid = (const float*)d_in[3];
  const float* b_hid = (const float*)d_in[4];
  const float* w_out = (const float*)d_in[5];
  const float* b_out = (const float*)d_in[6];
  float* out = (float*)d_out;
  unsigned short* wbf = (unsigned short*)d_ws;  // 131072 bytes used

  // arrange weights fp32 -> bf16 frag-linear image (re-done every launch)
  wconvert_kernel<<<W_ELEMS / 256, 256, 0, stream>>>(w_in, w_hid, w_out, wbf);

  // allow >64KB dynamic LDS (gfx950 has 160KB/CU)
  (void)hipFuncSetAttribute((const void*)mlp_kernel,
                            hipFuncAttributeMaxDynamicSharedMemorySize, LDS_BYTES);

  mlp_kernel<<<GRID, BLOCK, LDS_BYTES, stream>>>(x, wbf, b_in, b_hid, b_out, out);
}